// Round 8
// baseline (146.716 us; speedup 1.0000x reference)
//
#include <hip/hip_runtime.h>
#include <hip/hip_bf16.h>
#include <cstdint>
#include <cmath>

#define N_PIX 4096
#define CH    128
#define DD    64
#define NBATCH 8
#define NT    32    // 4096 / 128 key-tiles

typedef unsigned short u16;
typedef __attribute__((ext_vector_type(8))) short bf8_t;
typedef __attribute__((ext_vector_type(4))) float f4_t;
typedef __attribute__((ext_vector_type(16))) float f16v;
typedef uint32_t u32x4 __attribute__((ext_vector_type(4)));
typedef uint32_t u32x2 __attribute__((ext_vector_type(2)));

#define L2E 1.44269504088896340736f

// Native 2^x (single v_exp_f32). Plain exp2f without fast-math lowers to a
// denorm-guarded multi-instruction sequence; softmax tolerates flush-to-zero.
#if __has_builtin(__builtin_amdgcn_exp2f)
  #define EXP2(x) __builtin_amdgcn_exp2f(x)
#else
  #define EXP2(x) exp2f(x)
#endif

// Software RNE round (R5-verified call sites).
__device__ __forceinline__ u16 f2b(float f) {
  union { float f; uint32_t u; } v; v.f = f;
  uint32_t u = v.u;
  return (u16)((u + 0x7fffu + ((u >> 16) & 1u)) >> 16);
}
__device__ __forceinline__ float b2f(u16 h) {
  union { uint32_t u; float f; } v; v.u = ((uint32_t)h) << 16;
  return v.f;
}
__device__ __forceinline__ uint32_t pack2(float a, float b) {
  return (uint32_t)f2b(a) | ((uint32_t)f2b(b) << 16);
}
// Hardware bf16 convert path (scalar casts; compiler emits v_cvt[_pk]_bf16).
__device__ __forceinline__ uint32_t pack2hw(float a, float b) {
  u16 lo = __builtin_bit_cast(u16, __float2bfloat16(a));
  u16 hi = __builtin_bit_cast(u16, __float2bfloat16(b));
  return (uint32_t)lo | ((uint32_t)hi << 16);
}
__device__ __forceinline__ f4_t mfma16(bf8_t a, bf8_t b, f4_t c) {
  return __builtin_amdgcn_mfma_f32_16x16x32_bf16(a, b, c, 0, 0, 0);
}
__device__ __forceinline__ f16v mfma32(bf8_t a, bf8_t b, f16v c) {
  return __builtin_amdgcn_mfma_f32_32x32x16_bf16(a, b, c, 0, 0, 0);
}
// Compiler-modeled permlane32 swap. SAFE ONLY ON DISTINCT VALUES (R3/R6
// lesson: same-value operands degenerate to a self half-swap). Cross-half
// reduces use __shfl_xor(x,32).
__device__ __forceinline__ void pl32swap(uint32_t &a, uint32_t &b) {
  u32x2 r = __builtin_amdgcn_permlane32_swap(a, b, false, false);
  a = r[0];
  b = r[1];
}

// ---------------------------------------------------------------------------
// Kernel 1: fused projections. theta is PRE-SCALED by log2(e) so the attention
// softmax can use native exp2. theta_h[b][n][64], phi_h[b][n][64],
// gt_h[b][64][n] (bf16, bias included). (Unchanged, validated.)
// ---------------------------------------------------------------------------
__global__ __launch_bounds__(256) void proj_kernel(
    const float* __restrict__ x,
    const float* __restrict__ tw, const float* __restrict__ tb,
    const float* __restrict__ pw, const float* __restrict__ pb,
    const float* __restrict__ gw, const float* __restrict__ gb,
    u16* __restrict__ theta_h, u16* __restrict__ phi_h, u16* __restrict__ gt_h) {
  __shared__ __align__(16) u16 xT[64][136];
  const int blk = blockIdx.x;
  const int b  = blk >> 6;
  const int n0 = (blk & 63) << 6;
  const int tid = threadIdx.x;

  #pragma unroll
  for (int i = 0; i < 8; ++i) {
    int idx = tid + i * 256;
    int px = (idx & 15) * 4;
    int c  = idx >> 4;
    float4 v = *(const float4*)(x + ((size_t)b * CH + c) * N_PIX + n0 + px);
    xT[px + 0][c] = f2b(v.x);
    xT[px + 1][c] = f2b(v.y);
    xT[px + 2][c] = f2b(v.z);
    xT[px + 3][c] = f2b(v.w);
  }
  __syncthreads();

  const int lane = tid & 63;
  const int w    = tid >> 6;
  const int l4   = lane >> 4, l15 = lane & 15;

  bf8_t bw[3][4];
  float bias[3];
  #pragma unroll
  for (int nt = 0; nt < 3; ++nt) {
    int op = 16 * (3 * w + nt) + l15;
    const float* wrow; float bv; float scl;
    if (op < 64)       { wrow = tw + op * CH;          bv = tb[op];        scl = L2E; }
    else if (op < 128) { wrow = pw + (op - 64) * CH;   bv = pb[op - 64];   scl = 1.f; }
    else               { wrow = gw + (op - 128) * CH;  bv = gb[op - 128];  scl = 1.f; }
    bias[nt] = bv * scl;
    #pragma unroll
    for (int ks = 0; ks < 4; ++ks) {
      const float* p = wrow + 32 * ks + l4 * 8;
      bf8_t v;
      #pragma unroll
      for (int j = 0; j < 8; ++j) v[j] = (short)f2b(p[j] * scl);
      bw[nt][ks] = v;
    }
  }

  f4_t acc[4][3];
  #pragma unroll
  for (int mt = 0; mt < 4; ++mt)
    #pragma unroll
    for (int nt = 0; nt < 3; ++nt) acc[mt][nt] = (f4_t){0.f, 0.f, 0.f, 0.f};

  #pragma unroll
  for (int mt = 0; mt < 4; ++mt) {
    #pragma unroll
    for (int ks = 0; ks < 4; ++ks) {
      bf8_t a = *(const bf8_t*)&xT[l15 + 16 * mt][32 * ks + l4 * 8];
      #pragma unroll
      for (int nt = 0; nt < 3; ++nt)
        acc[mt][nt] = mfma16(a, bw[nt][ks], acc[mt][nt]);
    }
  }

  #pragma unroll
  for (int nt = 0; nt < 3; ++nt) {
    int op = 16 * (3 * w + nt) + l15;
    #pragma unroll
    for (int mt = 0; mt < 4; ++mt) {
      #pragma unroll
      for (int r = 0; r < 4; ++r) {
        int q = n0 + 16 * mt + l4 * 4 + r;
        u16 h = f2b(acc[mt][nt][r] + bias[nt]);
        if (op < 64)       theta_h[((size_t)b * N_PIX + q) * DD + op] = h;
        else if (op < 128) phi_h[((size_t)b * N_PIX + q) * DD + (op - 64)] = h;
        else               gt_h[((size_t)b * DD + (op - 128)) * N_PIX + q] = h;
      }
    }
  }
}

// ---------------------------------------------------------------------------
// Kernel 2: flash attention, DE-STAGED K/V (L2-resident per XCD, guide
// common-mistake #7): phi and gt are read directly global->registers in the
// exact MFMA fragment pattern — no LDS staging, no ds_writes, NO inner-loop
// barrier (waves run free). phi loads issue first (QK needs them); gt loads
// drain under QK+softmax. Softmax/pack/PV identical to green R7. LDS holds
// only the 34KB merge buffer behind the two post-loop barriers.
// ---------------------------------------------------------------------------
__global__ __launch_bounds__(512, 4) void attn_kernel(
    const u16* __restrict__ theta_h, const u16* __restrict__ phi_h,
    const u16* __restrict__ gt_h, u16* __restrict__ y_h) {
  __shared__ __align__(16) u16 smem[17408];   // 32KB ypart + 2KB m/l

  const int bid = blockIdx.x;                  // 512 blocks, 512 % 8 == 0
  const int lb  = (bid & 7) * 64 + (bid >> 3); // XCD swizzle: batch per XCD
  const int b   = lb >> 6;
  const int q0  = (lb & 63) << 6;
  const int tid = threadIdx.x;
  const int l   = tid & 63;
  const int w   = tid >> 6;
  const int qg  = w & 1;    // q-group (32 q)
  const int mh  = w >> 1;   // m-slice (32 of each 128-key tile)
  const int l31 = l & 31;
  const int hi  = l >> 5;

  // theta B-fragments (base-2-scaled): theta[q = q0+32qg+l31][k = 16kk+8hi..]
  bf8_t th[4];
  {
    const u16* trow = theta_h + ((size_t)b * N_PIX + q0 + 32 * qg + l31) * DD;
    #pragma unroll
    for (int kk = 0; kk < 4; ++kk)
      th[kk] = *(const bf8_t*)(trow + 16 * kk + 8 * hi);
  }

  f16v yacc[2];
  #pragma unroll
  for (int ot = 0; ot < 2; ++ot)
    #pragma unroll
    for (int r = 0; r < 16; ++r) yacc[ot][r] = 0.f;
  float m_ = -1e30f, l_ = 0.f;   // l_ = own half only; combined after loop

  // Per-lane global fragment pointers (advance per tile):
  //  phi A-frag: row = t*128 + 32*mh + l31, chunk (2kk+hi)*8
  const u16* pP = phi_h + ((size_t)b * N_PIX + 32 * mh + l31) * DD + 8 * hi;
  //  gt  A-frag: row o = 32*ot + l31, cols t*128 + mh*32 + hi*8 + {0,16}
  const u16* pG0 = gt_h + ((size_t)b * DD + l31) * N_PIX + mh * 32 + 8 * hi;
  const u16* pG1 = pG0 + 32 * (size_t)N_PIX;

  for (int t = 0; t < NT; ++t) {
    // phi first (QK consumes immediately), gt after (drains under softmax)
    bf8_t a0 = *(const bf8_t*)(pP);
    bf8_t a1 = *(const bf8_t*)(pP + 16);
    bf8_t a2 = *(const bf8_t*)(pP + 32);
    bf8_t a3 = *(const bf8_t*)(pP + 48);
    bf8_t g00 = *(const bf8_t*)(pG0);
    bf8_t g01 = *(const bf8_t*)(pG0 + 16);
    bf8_t g10 = *(const bf8_t*)(pG1);
    bf8_t g11 = *(const bf8_t*)(pG1 + 16);
    pP += 128 * DD;
    pG0 += 128;
    pG1 += 128;

    // ---- QK^T (swapped): ST[m][q], 4 x mfma32 over K=64 ------------------
    f16v st;
    #pragma unroll
    for (int r = 0; r < 16; ++r) st[r] = 0.f;
    st = mfma32(a0, th[0], st);
    st = mfma32(a1, th[1], st);
    st = mfma32(a2, th[2], st);
    st = mfma32(a3, th[3], st);

    // ---- max: balanced tree + cross-half shfl (verified) -----------------
    float x0 = fmaxf(st[0], st[1]),   x1 = fmaxf(st[2], st[3]);
    float x2 = fmaxf(st[4], st[5]),   x3 = fmaxf(st[6], st[7]);
    float x4 = fmaxf(st[8], st[9]),   x5 = fmaxf(st[10], st[11]);
    float x6 = fmaxf(st[12], st[13]), x7 = fmaxf(st[14], st[15]);
    float y0 = fmaxf(fmaxf(x0, x1), fmaxf(x2, x3));
    float y1 = fmaxf(fmaxf(x4, x5), fmaxf(x6, x7));
    float pmax = fmaxf(y0, y1);
    pmax = fmaxf(pmax, __shfl_xor(pmax, 32));

    // ---- defer-max (T13): rescale only when running max grows > 2^8 ------
    if (!__all(pmax <= m_ + 8.f)) {
      float mn = fmaxf(m_, pmax);
      float sc = EXP2(m_ - mn);
      m_ = mn;
      l_ *= sc;
      #pragma unroll
      for (int ot = 0; ot < 2; ++ot)
        #pragma unroll
        for (int r = 0; r < 16; ++r) yacc[ot][r] *= sc;
    }

    // ---- P = 2^(st - m), balanced-tree row sum (own half only) -----------
    #pragma unroll
    for (int r = 0; r < 16; ++r) st[r] = EXP2(st[r] - m_);
    float s0 = st[0] + st[1],   s1 = st[2] + st[3];
    float s2 = st[4] + st[5],   s3 = st[6] + st[7];
    float s4 = st[8] + st[9],   s5 = st[10] + st[11];
    float s6 = st[12] + st[13], s7 = st[14] + st[15];
    float t0 = (s0 + s1) + (s2 + s3);
    float t1 = (s4 + s5) + (s6 + s7);
    l_ += t0 + t1;

    // ---- P -> PV B-fragments (hw-cast pack + permlane swap, distinct) ----
    uint32_t c0 = pack2hw(st[0],  st[1]),  c1 = pack2hw(st[2],  st[3]);
    uint32_t c2 = pack2hw(st[4],  st[5]),  c3 = pack2hw(st[6],  st[7]);
    uint32_t c4 = pack2hw(st[8],  st[9]),  c5 = pack2hw(st[10], st[11]);
    uint32_t c6 = pack2hw(st[12], st[13]), c7 = pack2hw(st[14], st[15]);
    pl32swap(c0, c2); pl32swap(c1, c3);
    pl32swap(c4, c6); pl32swap(c5, c7);
    bf8_t pf0 = __builtin_bit_cast(bf8_t, (u32x4){c0, c1, c2, c3}); // m 0..15
    bf8_t pf1 = __builtin_bit_cast(bf8_t, (u32x4){c4, c5, c6, c7}); // m 16..31

    // ---- PV: y^T[o][q] += gt[o][m] . P^T[m][q] ---------------------------
    yacc[0] = mfma32(g00, pf0, yacc[0]);
    yacc[0] = mfma32(g01, pf1, yacc[0]);
    yacc[1] = mfma32(g10, pf0, yacc[1]);
    yacc[1] = mfma32(g11, pf1, yacc[1]);
  }

  // deferred cross-half sum combine (pair has identical rescale history)
  l_ += __shfl_xor(l_, 32);

  // ---- 4-way flash merge across m-slices ----------------------------------
  #pragma unroll
  for (int ot = 0; ot < 2; ++ot)
    #pragma unroll
    for (int r = 0; r < 16; ++r) {
      int o = 32 * ot + (r & 3) + 8 * (r >> 2) + 4 * hi;
      smem[(((qg * 4 + mh) * 64 + o) << 5) + l31] = f2b(yacc[ot][r]);
    }
  float* ml = (float*)(smem + 16384);
  if (hi == 0) {
    ml[(qg * 4 + mh) * 64 + l31]      = m_;
    ml[(qg * 4 + mh) * 64 + 32 + l31] = l_;
  }
  __syncthreads();

  {
    const int qg2 = tid >> 8;
    const int rem = tid & 255;
    const int qq  = rem & 31;
    const int og  = rem >> 5;
    float mi[4], li[4];
    #pragma unroll
    for (int i = 0; i < 4; ++i) {
      mi[i] = ml[(qg2 * 4 + i) * 64 + qq];
      li[i] = ml[(qg2 * 4 + i) * 64 + 32 + qq];
    }
    float M = fmaxf(fmaxf(mi[0], mi[1]), fmaxf(mi[2], mi[3]));
    float e[4], L = 0.f;
    #pragma unroll
    for (int i = 0; i < 4; ++i) { e[i] = EXP2(mi[i] - M); L += li[i] * e[i]; }
    float invL = 1.0f / L;
    float acc[8];
    #pragma unroll
    for (int oo = 0; oo < 8; ++oo) {
      int o = og * 8 + oo;
      float a = 0.f;
      #pragma unroll
      for (int i = 0; i < 4; ++i)
        a += b2f(smem[(((qg2 * 4 + i) * 64 + o) << 5) + qq]) * e[i];
      acc[oo] = a * invL;
    }
    uint4 ov;
    ov.x = pack2(acc[0], acc[1]);
    ov.y = pack2(acc[2], acc[3]);
    ov.z = pack2(acc[4], acc[5]);
    ov.w = pack2(acc[6], acc[7]);
    *(uint4*)(y_h + ((size_t)b * N_PIX + q0 + 32 * qg2 + qq) * DD + og * 8) = ov;
  }
}

// ---------------------------------------------------------------------------
// Kernel 3: out = out_w @ y + out_b + x (unchanged, validated).
// ---------------------------------------------------------------------------
__global__ __launch_bounds__(256) void outproj_kernel(
    const u16* __restrict__ y_h, const float* __restrict__ ow,
    const float* __restrict__ ob, const float* __restrict__ x,
    float* __restrict__ out) {
  __shared__ __align__(16) float ot[128][68];
  const int blk = blockIdx.x;
  const int b  = blk >> 6;
  const int n0 = (blk & 63) << 6;
  const int tid = threadIdx.x;
  const int lane = tid & 63;
  const int w    = tid >> 6;
  const int l4   = lane >> 4, l15 = lane & 15;

  bf8_t bw[2][2];
  float bias[2];
  #pragma unroll
  for (int nt = 0; nt < 2; ++nt) {
    int c = 16 * (2 * w + nt) + l15;
    bias[nt] = ob[c];
    #pragma unroll
    for (int ks = 0; ks < 2; ++ks) {
      const float* p = ow + c * DD + 32 * ks + l4 * 8;
      bf8_t v;
      #pragma unroll
      for (int j = 0; j < 8; ++j) v[j] = (short)f2b(p[j]);
      bw[nt][ks] = v;
    }
  }

  f4_t acc[4][2];
  #pragma unroll
  for (int mt = 0; mt < 4; ++mt)
    #pragma unroll
    for (int nt = 0; nt < 2; ++nt) acc[mt][nt] = (f4_t){0.f, 0.f, 0.f, 0.f};

  #pragma unroll
  for (int mt = 0; mt < 4; ++mt) {
    const u16* yr = y_h + ((size_t)b * N_PIX + n0 + 16 * mt + l15) * DD + l4 * 8;
    bf8_t a0 = *(const bf8_t*)yr;
    bf8_t a1 = *(const bf8_t*)(yr + 32);
    #pragma unroll
    for (int nt = 0; nt < 2; ++nt) {
      acc[mt][nt] = mfma16(a0, bw[nt][0], acc[mt][nt]);
      acc[mt][nt] = mfma16(a1, bw[nt][1], acc[mt][nt]);
    }
  }

  #pragma unroll
  for (int nt = 0; nt < 2; ++nt) {
    int c = 16 * (2 * w + nt) + l15;
    #pragma unroll
    for (int mt = 0; mt < 4; ++mt)
      #pragma unroll
      for (int r = 0; r < 4; ++r)
        ot[c][16 * mt + l4 * 4 + r] = acc[mt][nt][r] + bias[nt];
  }
  __syncthreads();

  #pragma unroll
  for (int i = 0; i < 8; ++i) {
    int idx = tid + i * 256;
    int px = (idx & 15) * 4;
    int c  = idx >> 4;
    size_t gi = ((size_t)b * CH + c) * N_PIX + n0 + px;
    float4 xv = *(const float4*)(x + gi);
    float4 o;
    o.x = ot[c][px + 0] + xv.x;
    o.y = ot[c][px + 1] + xv.y;
    o.z = ot[c][px + 2] + xv.z;
    o.w = ot[c][px + 3] + xv.w;
    *(float4*)(out + gi) = o;
  }
}

extern "C" void kernel_launch(void* const* d_in, const int* in_sizes, int n_in,
                              void* d_out, int out_size, void* d_ws, size_t ws_size,
                              hipStream_t stream) {
  const float* x  = (const float*)d_in[0];
  const float* tw = (const float*)d_in[1];
  const float* tb = (const float*)d_in[2];
  const float* pw = (const float*)d_in[3];
  const float* pb = (const float*)d_in[4];
  const float* gw = (const float*)d_in[5];
  const float* gb = (const float*)d_in[6];
  const float* ow = (const float*)d_in[7];
  const float* ob = (const float*)d_in[8];
  float* out = (float*)d_out;

  const size_t sz = (size_t)NBATCH * N_PIX * DD;
  u16* theta_h = (u16*)d_ws;
  u16* phi_h   = theta_h + sz;
  u16* gt_h    = phi_h + sz;
  u16* y_h     = gt_h + sz;

  proj_kernel<<<512, 256, 0, stream>>>(x, tw, tb, pw, pb, gw, gb, theta_h, phi_h, gt_h);
  attn_kernel<<<512, 512, 0, stream>>>(theta_h, phi_h, gt_h, y_h);
  outproj_kernel<<<512, 256, 0, stream>>>(y_h, ow, ob, x, out);
}

// Round 9
// 83.350 us; speedup vs baseline: 1.7602x; 1.7602x over previous
//
#include <hip/hip_runtime.h>
#include <hip/hip_bf16.h>
#include <cstdint>
#include <cmath>

#define N_PIX 4096
#define CH    128
#define DD    64
#define NBATCH 8
#define NT    32    // 4096 / 128 key-tiles

typedef unsigned short u16;
typedef __attribute__((ext_vector_type(8))) short bf8_t;
typedef __attribute__((ext_vector_type(4))) float f4_t;
typedef __attribute__((ext_vector_type(16))) float f16v;
typedef uint32_t u32x4 __attribute__((ext_vector_type(4)));
typedef uint32_t u32x2 __attribute__((ext_vector_type(2)));

#define L2E 1.44269504088896340736f

// Native 2^x (single v_exp_f32). Plain exp2f without fast-math lowers to a
// denorm-guarded multi-instruction sequence; softmax tolerates flush-to-zero.
#if __has_builtin(__builtin_amdgcn_exp2f)
  #define EXP2(x) __builtin_amdgcn_exp2f(x)
#else
  #define EXP2(x) exp2f(x)
#endif

// Hardware bf16 convert (v_cvt[_pk]_bf16_f32, RNE — same rounding as the old
// software round; P-path ran green on this in R7).
__device__ __forceinline__ u16 f2b(float f) {
  return __builtin_bit_cast(u16, __float2bfloat16(f));
}
__device__ __forceinline__ float b2f(u16 h) {
  union { uint32_t u; float f; } v; v.u = ((uint32_t)h) << 16;
  return v.f;
}
__device__ __forceinline__ uint32_t pack2(float a, float b) {
  return (uint32_t)f2b(a) | ((uint32_t)f2b(b) << 16);
}
__device__ __forceinline__ f4_t mfma16(bf8_t a, bf8_t b, f4_t c) {
  return __builtin_amdgcn_mfma_f32_16x16x32_bf16(a, b, c, 0, 0, 0);
}
__device__ __forceinline__ f16v mfma32(bf8_t a, bf8_t b, f16v c) {
  return __builtin_amdgcn_mfma_f32_32x32x16_bf16(a, b, c, 0, 0, 0);
}
// Compiler-modeled permlane32 swap. SAFE ONLY ON DISTINCT VALUES (R3/R6
// lesson: same-value operands degenerate to a self half-swap). Cross-half
// reduces use __shfl_xor(x,32).
__device__ __forceinline__ void pl32swap(uint32_t &a, uint32_t &b) {
  u32x2 r = __builtin_amdgcn_permlane32_swap(a, b, false, false);
  a = r[0];
  b = r[1];
}

// ---------------------------------------------------------------------------
// Kernel 1: fused projections. theta is PRE-SCALED by log2(e) so the attention
// softmax can use native exp2. theta_h[b][n][64], phi_h[b][n][64],
// gt_h[b][64][n] (bf16, bias included).
// ---------------------------------------------------------------------------
__global__ __launch_bounds__(256) void proj_kernel(
    const float* __restrict__ x,
    const float* __restrict__ tw, const float* __restrict__ tb,
    const float* __restrict__ pw, const float* __restrict__ pb,
    const float* __restrict__ gw, const float* __restrict__ gb,
    u16* __restrict__ theta_h, u16* __restrict__ phi_h, u16* __restrict__ gt_h) {
  __shared__ __align__(16) u16 xT[64][136];
  const int blk = blockIdx.x;
  const int b  = blk >> 6;
  const int n0 = (blk & 63) << 6;
  const int tid = threadIdx.x;

  #pragma unroll
  for (int i = 0; i < 8; ++i) {
    int idx = tid + i * 256;
    int px = (idx & 15) * 4;
    int c  = idx >> 4;
    float4 v = *(const float4*)(x + ((size_t)b * CH + c) * N_PIX + n0 + px);
    xT[px + 0][c] = f2b(v.x);
    xT[px + 1][c] = f2b(v.y);
    xT[px + 2][c] = f2b(v.z);
    xT[px + 3][c] = f2b(v.w);
  }
  __syncthreads();

  const int lane = tid & 63;
  const int w    = tid >> 6;
  const int l4   = lane >> 4, l15 = lane & 15;

  bf8_t bw[3][4];
  float bias[3];
  #pragma unroll
  for (int nt = 0; nt < 3; ++nt) {
    int op = 16 * (3 * w + nt) + l15;
    const float* wrow; float bv; float scl;
    if (op < 64)       { wrow = tw + op * CH;          bv = tb[op];        scl = L2E; }
    else if (op < 128) { wrow = pw + (op - 64) * CH;   bv = pb[op - 64];   scl = 1.f; }
    else               { wrow = gw + (op - 128) * CH;  bv = gb[op - 128];  scl = 1.f; }
    bias[nt] = bv * scl;
    #pragma unroll
    for (int ks = 0; ks < 4; ++ks) {
      const float* p = wrow + 32 * ks + l4 * 8;
      bf8_t v;
      #pragma unroll
      for (int j = 0; j < 8; ++j) v[j] = (short)f2b(p[j] * scl);
      bw[nt][ks] = v;
    }
  }

  f4_t acc[4][3];
  #pragma unroll
  for (int mt = 0; mt < 4; ++mt)
    #pragma unroll
    for (int nt = 0; nt < 3; ++nt) acc[mt][nt] = (f4_t){0.f, 0.f, 0.f, 0.f};

  #pragma unroll
  for (int mt = 0; mt < 4; ++mt) {
    #pragma unroll
    for (int ks = 0; ks < 4; ++ks) {
      bf8_t a = *(const bf8_t*)&xT[l15 + 16 * mt][32 * ks + l4 * 8];
      #pragma unroll
      for (int nt = 0; nt < 3; ++nt)
        acc[mt][nt] = mfma16(a, bw[nt][ks], acc[mt][nt]);
    }
  }

  #pragma unroll
  for (int nt = 0; nt < 3; ++nt) {
    int op = 16 * (3 * w + nt) + l15;
    #pragma unroll
    for (int mt = 0; mt < 4; ++mt) {
      #pragma unroll
      for (int r = 0; r < 4; ++r) {
        int q = n0 + 16 * mt + l4 * 4 + r;
        u16 h = f2b(acc[mt][nt][r] + bias[nt]);
        if (op < 64)       theta_h[((size_t)b * N_PIX + q) * DD + op] = h;
        else if (op < 128) phi_h[((size_t)b * N_PIX + q) * DD + (op - 64)] = h;
        else               gt_h[((size_t)b * DD + (op - 128)) * N_PIX + q] = h;
      }
    }
  }
}

// ---------------------------------------------------------------------------
// Kernel 2: flash attention, 32x32 MFMA, swapped QK^T, in-register P path.
// REVERTED to the R7 staged structure (R8's de-staging was request/latency
// bound: per-lane gathers hit ~32 cache lines/instr and lost the 1-tile
// prefetch distance). Tweaks on top of R7: setprio around MFMA clusters (T5,
// m191), unroll 2 to fold LDS buffer addresses, hw bf16 casts everywhere.
// ---------------------------------------------------------------------------
__global__ __launch_bounds__(512, 4) void attn_kernel(
    const u16* __restrict__ theta_h, const u16* __restrict__ phi_h,
    const u16* __restrict__ gt_h, u16* __restrict__ y_h) {
  __shared__ __align__(16) u16 smem[32768];   // 64 KiB: 2 bufs x (phi|gt)

  const int bid = blockIdx.x;                  // 512 blocks, 512 % 8 == 0
  const int lb  = (bid & 7) * 64 + (bid >> 3); // XCD swizzle: batch per XCD
  const int b   = lb >> 6;
  const int q0  = (lb & 63) << 6;
  const int tid = threadIdx.x;
  const int l   = tid & 63;
  const int w   = tid >> 6;
  const int qg  = w & 1;    // q-group (32 q)
  const int mh  = w >> 1;   // m-slice (32 of each 128-key tile)
  const int l31 = l & 31;
  const int hi  = l >> 5;

  // theta B-fragments (base-2-scaled): theta[q = q0+32qg+l31][k = 16kk+8hi..]
  bf8_t th[4];
  {
    const u16* trow = theta_h + ((size_t)b * N_PIX + q0 + 32 * qg + l31) * DD;
    #pragma unroll
    for (int kk = 0; kk < 4; ++kk)
      th[kk] = *(const bf8_t*)(trow + 16 * kk + 8 * hi);
  }

  f16v yacc[2];
  #pragma unroll
  for (int ot = 0; ot < 2; ++ot)
    #pragma unroll
    for (int r = 0; r < 16; ++r) yacc[ot][r] = 0.f;
  float m_ = -1e30f, l_ = 0.f;   // l_ = own half only; combined after loop

  // ---- staging addresses (per thread: 2 phi chunks + 2 gt chunks of 16B) --
  const int pr  = tid >> 3, pc = tid & 7;
  const int go  = tid >> 4, gc = tid & 15;
  const u16* phA = phi_h + ((size_t)b * N_PIX + pr) * DD + pc * 8;
  const u16* gtA = gt_h + ((size_t)b * DD + go) * N_PIX + gc * 8;
  const int pO0 = pr * 64 + ((pc ^ (pr & 7)) << 3);
  const int pO1 = pO0 + 4096;
  const int gO0 = 8192 + go * 128 + ((gc ^ (go & 7)) << 3);
  const int gO1 = gO0 + 4096;

  uint4 v0, v1, v2, v3;
  #define LOADS(kb_) do {                                              \
    v0 = *(const uint4*)(phA + (size_t)(kb_) * 8192);                  \
    v1 = *(const uint4*)(phA + (size_t)(kb_) * 8192 + 4096);           \
    v2 = *(const uint4*)(gtA + (size_t)(kb_) * 128);                   \
    v3 = *(const uint4*)(gtA + (size_t)(kb_) * 128 + 32 * (size_t)N_PIX); \
  } while (0)
  #define WRITES(buf_) do {                                            \
    u16* base_ = smem + (buf_) * 16384;                                \
    *(uint4*)(base_ + pO0) = v0;                                       \
    *(uint4*)(base_ + pO1) = v1;                                       \
    *(uint4*)(base_ + gO0) = v2;                                       \
    *(uint4*)(base_ + gO1) = v3;                                       \
  } while (0)

  LOADS(0); WRITES(0);
  __syncthreads();

  const int prow  = 32 * mh + l31;
  const int pbase = prow * 64;
  const int pkey  = prow & 7;

  #pragma unroll 2
  for (int t = 0; t < NT; ++t) {
    const int cur = t & 1;
    if (t < NT - 1) LOADS(t + 1);
    const u16* pb = smem + cur * 16384;
    const u16* gb = pb + 8192;

    // ---- QK^T (swapped): ST[m][q], 4 x mfma32 over K=64 ------------------
    f16v st;
    #pragma unroll
    for (int r = 0; r < 16; ++r) st[r] = 0.f;
    __builtin_amdgcn_s_setprio(1);
    #pragma unroll
    for (int kk = 0; kk < 4; ++kk) {
      bf8_t a = *(const bf8_t*)(pb + pbase + (((2 * kk + hi) ^ pkey) << 3));
      st = mfma32(a, th[kk], st);
    }
    __builtin_amdgcn_s_setprio(0);

    // ---- max: balanced tree + cross-half shfl (verified) -----------------
    float x0 = fmaxf(st[0], st[1]),   x1 = fmaxf(st[2], st[3]);
    float x2 = fmaxf(st[4], st[5]),   x3 = fmaxf(st[6], st[7]);
    float x4 = fmaxf(st[8], st[9]),   x5 = fmaxf(st[10], st[11]);
    float x6 = fmaxf(st[12], st[13]), x7 = fmaxf(st[14], st[15]);
    float y0 = fmaxf(fmaxf(x0, x1), fmaxf(x2, x3));
    float y1 = fmaxf(fmaxf(x4, x5), fmaxf(x6, x7));
    float pmax = fmaxf(y0, y1);
    pmax = fmaxf(pmax, __shfl_xor(pmax, 32));

    // ---- defer-max (T13): rescale only when running max grows > 2^8 ------
    if (!__all(pmax <= m_ + 8.f)) {
      float mn = fmaxf(m_, pmax);
      float sc = EXP2(m_ - mn);
      m_ = mn;
      l_ *= sc;
      #pragma unroll
      for (int ot = 0; ot < 2; ++ot)
        #pragma unroll
        for (int r = 0; r < 16; ++r) yacc[ot][r] *= sc;
    }

    // ---- P = 2^(st - m), balanced-tree row sum (own half only) -----------
    #pragma unroll
    for (int r = 0; r < 16; ++r) st[r] = EXP2(st[r] - m_);
    float s0 = st[0] + st[1],   s1 = st[2] + st[3];
    float s2 = st[4] + st[5],   s3 = st[6] + st[7];
    float s4 = st[8] + st[9],   s5 = st[10] + st[11];
    float s6 = st[12] + st[13], s7 = st[14] + st[15];
    float t0 = (s0 + s1) + (s2 + s3);
    float t1 = (s4 + s5) + (s6 + s7);
    l_ += t0 + t1;   // cross-half combine deferred to after the loop

    // ---- P -> PV B-fragments (hw cvt_pk + permlane swap, distinct) -------
    uint32_t c0 = pack2(st[0],  st[1]),  c1 = pack2(st[2],  st[3]);
    uint32_t c2 = pack2(st[4],  st[5]),  c3 = pack2(st[6],  st[7]);
    uint32_t c4 = pack2(st[8],  st[9]),  c5 = pack2(st[10], st[11]);
    uint32_t c6 = pack2(st[12], st[13]), c7 = pack2(st[14], st[15]);
    pl32swap(c0, c2); pl32swap(c1, c3);
    pl32swap(c4, c6); pl32swap(c5, c7);
    bf8_t pf0 = __builtin_bit_cast(bf8_t, (u32x4){c0, c1, c2, c3}); // m 0..15
    bf8_t pf1 = __builtin_bit_cast(bf8_t, (u32x4){c4, c5, c6, c7}); // m 16..31

    // ---- PV: y^T[o][q] += gt[o][m] . P^T[m][q] ---------------------------
    __builtin_amdgcn_s_setprio(1);
    #pragma unroll
    for (int ot = 0; ot < 2; ++ot) {
      int orow  = 32 * ot + l31;
      int obase = orow * 128;
      int okey  = orow & 7;
      bf8_t g0 = *(const bf8_t*)(gb + obase + ((((mh << 2) + hi)     ^ okey) << 3));
      yacc[ot] = mfma32(g0, pf0, yacc[ot]);
      bf8_t g1 = *(const bf8_t*)(gb + obase + ((((mh << 2) + 2 + hi) ^ okey) << 3));
      yacc[ot] = mfma32(g1, pf1, yacc[ot]);
    }
    __builtin_amdgcn_s_setprio(0);

    if (t < NT - 1) WRITES(cur ^ 1);
    __syncthreads();
  }
  #undef LOADS
  #undef WRITES

  // deferred cross-half sum combine (pair has identical rescale history)
  l_ += __shfl_xor(l_, 32);

  // ---- 4-way flash merge across m-slices (reuse smem) ---------------------
  #pragma unroll
  for (int ot = 0; ot < 2; ++ot)
    #pragma unroll
    for (int r = 0; r < 16; ++r) {
      int o = 32 * ot + (r & 3) + 8 * (r >> 2) + 4 * hi;
      smem[(((qg * 4 + mh) * 64 + o) << 5) + l31] = f2b(yacc[ot][r]);
    }
  float* ml = (float*)(smem + 16384);
  if (hi == 0) {
    ml[(qg * 4 + mh) * 64 + l31]      = m_;
    ml[(qg * 4 + mh) * 64 + 32 + l31] = l_;
  }
  __syncthreads();

  {
    const int qg2 = tid >> 8;
    const int rem = tid & 255;
    const int qq  = rem & 31;
    const int og  = rem >> 5;
    float mi[4], li[4];
    #pragma unroll
    for (int i = 0; i < 4; ++i) {
      mi[i] = ml[(qg2 * 4 + i) * 64 + qq];
      li[i] = ml[(qg2 * 4 + i) * 64 + 32 + qq];
    }
    float M = fmaxf(fmaxf(mi[0], mi[1]), fmaxf(mi[2], mi[3]));
    float e[4], L = 0.f;
    #pragma unroll
    for (int i = 0; i < 4; ++i) { e[i] = EXP2(mi[i] - M); L += li[i] * e[i]; }
    float invL = 1.0f / L;
    float acc[8];
    #pragma unroll
    for (int oo = 0; oo < 8; ++oo) {
      int o = og * 8 + oo;
      float a = 0.f;
      #pragma unroll
      for (int i = 0; i < 4; ++i)
        a += b2f(smem[(((qg2 * 4 + i) * 64 + o) << 5) + qq]) * e[i];
      acc[oo] = a * invL;
    }
    uint4 ov;
    ov.x = pack2(acc[0], acc[1]);
    ov.y = pack2(acc[2], acc[3]);
    ov.z = pack2(acc[4], acc[5]);
    ov.w = pack2(acc[6], acc[7]);
    *(uint4*)(y_h + ((size_t)b * N_PIX + q0 + 32 * qg2 + qq) * DD + og * 8) = ov;
  }
}

// ---------------------------------------------------------------------------
// Kernel 3: out = out_w @ y + out_b + x (R7-validated; hw casts for weights).
// ---------------------------------------------------------------------------
__global__ __launch_bounds__(256) void outproj_kernel(
    const u16* __restrict__ y_h, const float* __restrict__ ow,
    const float* __restrict__ ob, const float* __restrict__ x,
    float* __restrict__ out) {
  __shared__ __align__(16) float ot[128][68];
  const int blk = blockIdx.x;
  const int b  = blk >> 6;
  const int n0 = (blk & 63) << 6;
  const int tid = threadIdx.x;
  const int lane = tid & 63;
  const int w    = tid >> 6;
  const int l4   = lane >> 4, l15 = lane & 15;

  bf8_t bw[2][2];
  float bias[2];
  #pragma unroll
  for (int nt = 0; nt < 2; ++nt) {
    int c = 16 * (2 * w + nt) + l15;
    bias[nt] = ob[c];
    #pragma unroll
    for (int ks = 0; ks < 2; ++ks) {
      const float* p = ow + c * DD + 32 * ks + l4 * 8;
      bf8_t v;
      #pragma unroll
      for (int j = 0; j < 8; ++j) v[j] = (short)f2b(p[j]);
      bw[nt][ks] = v;
    }
  }

  f4_t acc[4][2];
  #pragma unroll
  for (int mt = 0; mt < 4; ++mt)
    #pragma unroll
    for (int nt = 0; nt < 2; ++nt) acc[mt][nt] = (f4_t){0.f, 0.f, 0.f, 0.f};

  #pragma unroll
  for (int mt = 0; mt < 4; ++mt) {
    const u16* yr = y_h + ((size_t)b * N_PIX + n0 + 16 * mt + l15) * DD + l4 * 8;
    bf8_t a0 = *(const bf8_t*)yr;
    bf8_t a1 = *(const bf8_t*)(yr + 32);
    #pragma unroll
    for (int nt = 0; nt < 2; ++nt) {
      acc[mt][nt] = mfma16(a0, bw[nt][0], acc[mt][nt]);
      acc[mt][nt] = mfma16(a1, bw[nt][1], acc[mt][nt]);
    }
  }

  #pragma unroll
  for (int nt = 0; nt < 2; ++nt) {
    int c = 16 * (2 * w + nt) + l15;
    #pragma unroll
    for (int mt = 0; mt < 4; ++mt)
      #pragma unroll
      for (int r = 0; r < 4; ++r)
        ot[c][16 * mt + l4 * 4 + r] = acc[mt][nt][r] + bias[nt];
  }
  __syncthreads();

  #pragma unroll
  for (int i = 0; i < 8; ++i) {
    int idx = tid + i * 256;
    int px = (idx & 15) * 4;
    int c  = idx >> 4;
    size_t gi = ((size_t)b * CH + c) * N_PIX + n0 + px;
    float4 xv = *(const float4*)(x + gi);
    float4 o;
    o.x = ot[c][px + 0] + xv.x;
    o.y = ot[c][px + 1] + xv.y;
    o.z = ot[c][px + 2] + xv.z;
    o.w = ot[c][px + 3] + xv.w;
    *(float4*)(out + gi) = o;
  }
}

extern "C" void kernel_launch(void* const* d_in, const int* in_sizes, int n_in,
                              void* d_out, int out_size, void* d_ws, size_t ws_size,
                              hipStream_t stream) {
  const float* x  = (const float*)d_in[0];
  const float* tw = (const float*)d_in[1];
  const float* tb = (const float*)d_in[2];
  const float* pw = (const float*)d_in[3];
  const float* pb = (const float*)d_in[4];
  const float* gw = (const float*)d_in[5];
  const float* gb = (const float*)d_in[6];
  const float* ow = (const float*)d_in[7];
  const float* ob = (const float*)d_in[8];
  float* out = (float*)d_out;

  const size_t sz = (size_t)NBATCH * N_PIX * DD;
  u16* theta_h = (u16*)d_ws;
  u16* phi_h   = theta_h + sz;
  u16* gt_h    = phi_h + sz;
  u16* y_h     = gt_h + sz;

  proj_kernel<<<512, 256, 0, stream>>>(x, tw, tb, pw, pb, gw, gb, theta_h, phi_h, gt_h);
  attn_kernel<<<512, 512, 0, stream>>>(theta_h, phi_h, gt_h, y_h);
  outproj_kernel<<<512, 256, 0, stream>>>(y_h, ow, ob, x, out);
}